// Round 1
// baseline (271.025 us; speedup 1.0000x reference)
//
#include <hip/hip_runtime.h>
#include <stdint.h>

typedef unsigned short u16;
typedef float f32x4 __attribute__((ext_vector_type(4)));
typedef __bf16 bf16x8 __attribute__((ext_vector_type(8)));

#define BS 2
#define SEQ 2048
#define DIM 1024
#define NW3 3072
#define NH 16
#define HD 64

#define MFMA_BF16(a, b, c) __builtin_amdgcn_mfma_f32_16x16x32_bf16((a), (b), (c), 0, 0, 0)

// async global->LDS, 16B per lane; LDS dest must be wave-uniform base + lane*16
#define GLL16(g, l)                                                                \
  __builtin_amdgcn_global_load_lds(                                                \
      (__attribute__((address_space(1))) void*)(void*)(uintptr_t)(g),              \
      (__attribute__((address_space(3))) void*)(l), 16, 0, 0)

__device__ __forceinline__ float fexp2(float x) {
#if defined(__has_builtin)
#if __has_builtin(__builtin_amdgcn_exp2f)
  return __builtin_amdgcn_exp2f(x);
#else
  return exp2f(x);
#endif
#else
  return exp2f(x);
#endif
}

__device__ __forceinline__ u16 f2bf(float x) {
  __bf16 h = (__bf16)x;
  return __builtin_bit_cast(u16, h);
}

// ---------------- fp32 -> bf16 straight convert (embeddings) ----------------
__global__ __launch_bounds__(256) void conv_a_kernel(const float* __restrict__ A,
                                                     u16* __restrict__ O) {
  int i = (blockIdx.x * 256 + threadIdx.x) * 4;
  float4 v = *(const float4*)(A + i);
  union { u16 u[4]; ushort4 v4; } p;
  p.u[0] = f2bf(v.x); p.u[1] = f2bf(v.y); p.u[2] = f2bf(v.z); p.u[3] = f2bf(v.w);
  *(ushort4*)(O + i) = p.v4;
}

// ---------------- W [k][n] fp32 -> Wt [n][k] bf16 (transposed) ----------------
__global__ __launch_bounds__(256) void conv_wt_kernel(const float* __restrict__ W,
                                                      u16* __restrict__ Wt) {
  int id = blockIdx.x * 256 + threadIdx.x;  // 0 .. 393215
  int kc = id / NW3;                        // 0..127 : chunk of 8 k's
  int n = id - kc * NW3;                    // consecutive lanes -> consecutive n (coalesced reads)
  union { u16 u[8]; uint4 v; } p;
#pragma unroll
  for (int i = 0; i < 8; ++i) p.u[i] = f2bf(W[(kc * 8 + i) * NW3 + n]);
  *(uint4*)(Wt + n * DIM + kc * 8) = p.v;
}

// ---------------- QKV GEMM: [4096x1024]x[1024x3072]+b, bf16 MFMA ----------------
// 128x128 tile, BK=64, global_load_lds w/ XOR-swizzled 16B chunks.
// Epilogue scatters heads: d = hd*16 + h (reference reshape), Q/K -> [b,h,s,hd], V -> [b,h,hd,s].
__global__ __launch_bounds__(256) void gemm_qkv_kernel(
    const u16* __restrict__ Ab, const u16* __restrict__ Bt, const float* __restrict__ bias,
    u16* __restrict__ Q, u16* __restrict__ K, u16* __restrict__ Vt) {
  __shared__ __align__(16) u16 Al[128 * 64];
  __shared__ __align__(16) u16 Bl[128 * 64];
  const int t = threadIdx.x;
  const int lane = t & 63, wave = t >> 6;
  const int c = lane & 15, quad = lane >> 4;
  const int tm = blockIdx.x / 24, tn = blockIdx.x - tm * 24;
  const int wm = (wave >> 1) * 64, wn = (wave & 1) * 64;

  const char* Abase = (const char*)(Ab + (size_t)tm * 128 * DIM);
  const char* Bbase = (const char*)(Bt + (size_t)tn * 128 * DIM);

  f32x4 z = {0.f, 0.f, 0.f, 0.f};
  f32x4 acc[4][4];
#pragma unroll
  for (int i = 0; i < 4; ++i)
#pragma unroll
    for (int j = 0; j < 4; ++j) acc[i][j] = z;

  for (int kt = 0; kt < 16; ++kt) {
    __syncthreads();
    const int koff = kt * 128;  // byte offset of k0 within a row
#pragma unroll
    for (int r = 0; r < 4; ++r) {
      int l = r * 256 + t;          // 16B chunk id, wave-contiguous
      int row = l >> 3, pos = l & 7;
      int kc = pos ^ (row & 7);     // XOR swizzle (global side)
      GLL16(Abase + row * 2048 + koff + kc * 16, (char*)Al + l * 16);
      GLL16(Bbase + row * 2048 + koff + kc * 16, (char*)Bl + l * 16);
    }
    __syncthreads();
#pragma unroll
    for (int ks = 0; ks < 2; ++ks) {
      bf16x8 af[4], bfr[4];
#pragma unroll
      for (int mt = 0; mt < 4; ++mt) {
        int row = wm + mt * 16 + c;
        int kc = (ks * 4 + quad) ^ (row & 7);
        af[mt] = *(const bf16x8*)((const char*)Al + row * 128 + kc * 16);
      }
#pragma unroll
      for (int nt = 0; nt < 4; ++nt) {
        int row = wn + nt * 16 + c;
        int kc = (ks * 4 + quad) ^ (row & 7);
        bfr[nt] = *(const bf16x8*)((const char*)Bl + row * 128 + kc * 16);
      }
#pragma unroll
      for (int mt = 0; mt < 4; ++mt)
#pragma unroll
        for (int nt = 0; nt < 4; ++nt)
          acc[mt][nt] = MFMA_BF16(af[mt], bfr[nt], acc[mt][nt]);
    }
  }

  // Epilogue: C/D layout col = lane&15, row = quad*4 + reg  (m89-verified)
#pragma unroll
  for (int nt = 0; nt < 4; ++nt) {
    int n = tn * 128 + wn + nt * 16 + c;
    float bv = bias[n];
    int which = n >> 10;   // 0=Q 1=K 2=V
    int rem = n & 1023;
    int hd = rem >> 4, h = rem & 15;   // d = hd*16 + h (interleaved head split)
#pragma unroll
    for (int mt = 0; mt < 4; ++mt) {
      int mbase = tm * 128 + wm + mt * 16 + quad * 4;
      int bI = mbase >> 11;      // mbase%4==0 -> same token block for all 4 regs
      int s0 = mbase & 2047;
      if (which == 2) {
        union { u16 u[4]; uint2 v; } p;
#pragma unroll
        for (int r = 0; r < 4; ++r) p.u[r] = f2bf(acc[mt][nt][r] + bv);
        *(uint2*)(Vt + ((size_t)(bI * NH + h) * HD + hd) * SEQ + s0) = p.v;  // [b,h,hd,s]
      } else {
        u16* dst = (which == 0) ? Q : K;
#pragma unroll
        for (int r = 0; r < 4; ++r)
          dst[((size_t)(bI * NH + h) * SEQ + (s0 + r)) * HD + hd] = f2bf(acc[mt][nt][r] + bv);
      }
    }
  }
}

// ---------------- Flash attention ----------------
// block = (b, h, 128 q rows), 4 waves x 32 q rows. Computes S^T = K*Q^T so that
// P^T's C-layout regs are consecutive s_k -> b64 LDS writes, b128 B-frag reads
// for O^T = V^T * P^T. Softmax state per (lane&15, nt), reduced via shfl_xor 16/32.
#define CSC 0.18033688011112042f  // 0.125 * log2(e)

__global__ __launch_bounds__(256) void attn_kernel(
    const u16* __restrict__ Q, const u16* __restrict__ K,
    const u16* __restrict__ Vt, float* __restrict__ Out) {
  __shared__ __align__(16) u16 Kl[128 * 64];   // 16 KB  (also reused for Q staging)
  __shared__ __align__(16) u16 Vl[64 * 128];   // 16 KB  V^T tile [hd][s_k]
  __shared__ __align__(16) char Pl[4 * 32 * 256];  // 32 KB, per-wave P^T [s_q][s_k]
  const int t = threadIdx.x;
  const int lane = t & 63, wave = t >> 6;
  const int c = lane & 15, quad = lane >> 4;
  const int qt = blockIdx.x & 15, bh = blockIdx.x >> 4;
  const int h = bh & 15, b = bh >> 4;

  const u16* Qb = Q + ((size_t)bh * SEQ + qt * 128) * HD;
  const u16* Kb = K + (size_t)bh * SEQ * HD;
  const u16* Vb = Vt + (size_t)bh * HD * SEQ;

  // stage Q tile through Kl, pull B-operand frags (Q[s_q][hd], k-contig)
#pragma unroll
  for (int r = 0; r < 4; ++r) {
    int l = r * 256 + t;
    int row = l >> 3, pos = l & 7;
    int kc = pos ^ (row & 7);
    GLL16((const char*)Qb + row * 128 + kc * 16, (char*)Kl + l * 16);
  }
  __syncthreads();
  bf16x8 qf[2][2];
#pragma unroll
  for (int nt = 0; nt < 2; ++nt)
#pragma unroll
    for (int ks = 0; ks < 2; ++ks) {
      int row = wave * 32 + nt * 16 + c;
      int kc = (ks * 4 + quad) ^ (row & 7);
      qf[nt][ks] = *(const bf16x8*)((const char*)Kl + row * 128 + kc * 16);
    }

  float mM[2] = {-__builtin_inff(), -__builtin_inff()};
  float lS[2] = {0.f, 0.f};
  f32x4 z = {0.f, 0.f, 0.f, 0.f};
  f32x4 accO[4][2];
#pragma unroll
  for (int i = 0; i < 4; ++i) { accO[i][0] = z; accO[i][1] = z; }
  char* Pw = Pl + wave * 8192;
  const int e = 2 * (c & 7);  // even XOR key for 8B-granule swizzle (pair-preserving)

  for (int kt = 0; kt < 16; ++kt) {
    __syncthreads();  // protect previous iter's LDS reads (and qf at kt==0)
    const char* Ktb = (const char*)(Kb + (size_t)kt * 128 * HD);
    const char* Vtb = (const char*)(Vb + (size_t)kt * 128);
#pragma unroll
    for (int r = 0; r < 4; ++r) {
      int l = r * 256 + t;
      { int row = l >> 3, pos = l & 7; int kc = pos ^ (row & 7);
        GLL16(Ktb + row * 128 + kc * 16, (char*)Kl + l * 16); }
      { int row = l >> 4, pos = l & 15; int kc = pos ^ (row & 15);
        GLL16(Vtb + row * 4096 + kc * 16, (char*)Vl + l * 16); }
    }
    __syncthreads();

    // S^T = K * Q^T : m = s_k (128 -> 8 tiles), n = s_q (32 -> 2 tiles), k = hd (64)
    f32x4 sT[8][2];
#pragma unroll
    for (int mt = 0; mt < 8; ++mt) { sT[mt][0] = z; sT[mt][1] = z; }
#pragma unroll
    for (int mt = 0; mt < 8; ++mt) {
#pragma unroll
      for (int ks = 0; ks < 2; ++ks) {
        int row = mt * 16 + c;
        int kc = (ks * 4 + quad) ^ (row & 7);
        bf16x8 kf = *(const bf16x8*)((const char*)Kl + row * 128 + kc * 16);
        sT[mt][0] = MFMA_BF16(kf, qf[0][ks], sT[mt][0]);
        sT[mt][1] = MFMA_BF16(kf, qf[1][ks], sT[mt][1]);
      }
    }

    // online softmax over s_k; per-lane state for s_q = nt*16 + c
#pragma unroll
    for (int nt = 0; nt < 2; ++nt) {
      float mx = -__builtin_inff();
#pragma unroll
      for (int mt = 0; mt < 8; ++mt)
#pragma unroll
        for (int r = 0; r < 4; ++r) mx = fmaxf(mx, sT[mt][nt][r]);
      mx = fmaxf(mx, __shfl_xor(mx, 16));
      mx = fmaxf(mx, __shfl_xor(mx, 32));
      float mnew = fmaxf(mM[nt], mx);
      float alpha = fexp2((mM[nt] - mnew) * CSC);  // exp2(-inf)=0 on first tile
      mM[nt] = mnew;
      float mc = mnew * CSC;
      float rs = 0.f;
#pragma unroll
      for (int mt = 0; mt < 8; ++mt)
#pragma unroll
        for (int r = 0; r < 4; ++r) {
          float p = fexp2(sT[mt][nt][r] * CSC - mc);
          sT[mt][nt][r] = p;
          rs += p;
        }
      rs += __shfl_xor(rs, 16);
      rs += __shfl_xor(rs, 32);
      lS[nt] = lS[nt] * alpha + rs;
#pragma unroll
      for (int mt = 0; mt < 4; ++mt)
#pragma unroll
        for (int r = 0; r < 4; ++r) accO[mt][nt][r] *= alpha;
      // write P^T[s_k][s_q] : regs are consecutive s_k -> packed b64 write
#pragma unroll
      for (int mt = 0; mt < 8; ++mt) {
        union { u16 u[4]; uint2 v; } p;
#pragma unroll
        for (int r = 0; r < 4; ++r) p.u[r] = f2bf(sT[mt][nt][r]);
        int g = 4 * mt + quad;                       // 8B granule along s_k
        *(uint2*)(Pw + (nt * 16 + c) * 256 + (g ^ e) * 8) = p.v;
      }
    }

    // O^T += V^T * P^T : m = hd (64 -> 4 tiles), n = s_q (2 tiles), k = s_k (128 -> 4 steps)
#pragma unroll
    for (int ks = 0; ks < 4; ++ks) {
      bf16x8 pf[2];
#pragma unroll
      for (int nt = 0; nt < 2; ++nt) {
        int g2 = 8 * ks + 2 * quad;                  // even -> swizzled pair stays adjacent
        pf[nt] = *(const bf16x8*)(Pw + (nt * 16 + c) * 256 + (g2 ^ e) * 8);
      }
#pragma unroll
      for (int mt = 0; mt < 4; ++mt) {
        int row = mt * 16 + c;
        int kc = (ks * 4 + quad) ^ (row & 15);
        bf16x8 vf = *(const bf16x8*)((const char*)Vl + row * 256 + kc * 16);
        accO[mt][0] = MFMA_BF16(vf, pf[0], accO[mt][0]);
        accO[mt][1] = MFMA_BF16(vf, pf[1], accO[mt][1]);
      }
    }
  }

  // epilogue: O^T C-layout -> out[b][s][h*64+hd], 4 consecutive hd per reg quad -> float4
#pragma unroll
  for (int nt = 0; nt < 2; ++nt) {
    float inv = 1.f / lS[nt];
    int s = qt * 128 + wave * 32 + nt * 16 + c;
#pragma unroll
    for (int mt = 0; mt < 4; ++mt) {
      float4 o;
      o.x = accO[mt][nt][0] * inv;
      o.y = accO[mt][nt][1] * inv;
      o.z = accO[mt][nt][2] * inv;
      o.w = accO[mt][nt][3] * inv;
      size_t off = ((size_t)(b * SEQ + s)) * DIM + h * HD + mt * 16 + quad * 4;
      *(float4*)(Out + off) = o;
    }
  }
}

extern "C" void kernel_launch(void* const* d_in, const int* in_sizes, int n_in,
                              void* d_out, int out_size, void* d_ws, size_t ws_size,
                              hipStream_t stream) {
  (void)in_sizes; (void)n_in; (void)out_size; (void)ws_size;
  const float* emb = (const float*)d_in[0];
  const float* W = (const float*)d_in[1];
  const float* bias = (const float*)d_in[2];
  float* out = (float*)d_out;
  char* ws = (char*)d_ws;
  // ws layout (bytes): Abf 8 MB | Wt 6 MB | Q 8 MB | K 8 MB | Vt 8 MB  (total ~38 MB)
  u16* Ab = (u16*)ws;
  u16* Wt = (u16*)(ws + 8388608);
  u16* Qd = (u16*)(ws + 14680064);
  u16* Kd = (u16*)(ws + 23068672);
  u16* Vd = (u16*)(ws + 31457280);

  conv_a_kernel<<<4096, 256, 0, stream>>>(emb, Ab);        // 4096*1024 elems / 4 per thread
  conv_wt_kernel<<<1536, 256, 0, stream>>>(W, Wt);         // 3072*128 chunk-threads
  gemm_qkv_kernel<<<768, 256, 0, stream>>>(Ab, Wt, bias, Qd, Kd, Vd);  // 32x24 tiles
  attn_kernel<<<512, 256, 0, stream>>>(Qd, Kd, Vd, out);   // 2*16*16 (b,h,qtile)
}

// Round 2
// 241.412 us; speedup vs baseline: 1.1227x; 1.1227x over previous
//
#include <hip/hip_runtime.h>
#include <stdint.h>

typedef unsigned short u16;
typedef unsigned int u32;
typedef float f32x4 __attribute__((ext_vector_type(4)));
typedef __bf16 bf16x8 __attribute__((ext_vector_type(8)));

#define BS 2
#define SEQ 2048
#define DIM 1024
#define NW3 3072
#define NH 16
#define HD 64

#define MFMA_BF16(a, b, c) __builtin_amdgcn_mfma_f32_16x16x32_bf16((a), (b), (c), 0, 0, 0)

// async global->LDS, 16B per lane; LDS dest must be wave-uniform base + lane*16
#define GLL16(g, l)                                                                \
  __builtin_amdgcn_global_load_lds(                                                \
      (__attribute__((address_space(1))) void*)(void*)(uintptr_t)(g),              \
      (__attribute__((address_space(3))) void*)(l), 16, 0, 0)

__device__ __forceinline__ float fexp2(float x) {
#if defined(__has_builtin)
#if __has_builtin(__builtin_amdgcn_exp2f)
  return __builtin_amdgcn_exp2f(x);
#else
  return exp2f(x);
#endif
#else
  return exp2f(x);
#endif
}

__device__ __forceinline__ u16 f2bf(float x) {
  __bf16 h = (__bf16)x;
  return __builtin_bit_cast(u16, h);
}

// ---------------- fp32 -> bf16 straight convert (embeddings) ----------------
__global__ __launch_bounds__(256) void conv_a_kernel(const float* __restrict__ A,
                                                     u16* __restrict__ O) {
  int i = (blockIdx.x * 256 + threadIdx.x) * 4;
  float4 v = *(const float4*)(A + i);
  union { u16 u[4]; ushort4 v4; } p;
  p.u[0] = f2bf(v.x); p.u[1] = f2bf(v.y); p.u[2] = f2bf(v.z); p.u[3] = f2bf(v.w);
  *(ushort4*)(O + i) = p.v4;
}

// ---------------- W [k][n] fp32 -> Wt [n'][k] bf16 (transposed + head-permuted) --
// Output ROW n' is head-grouped: n' = which*1024 + h*64 + hd  where the original
// column n = which*1024 + hd*16 + h. GEMM output columns then come out in
// (which, h, hd) order -> dense epilogue stores.
__global__ __launch_bounds__(256) void conv_wt_kernel(const float* __restrict__ W,
                                                      u16* __restrict__ Wt) {
  int id = blockIdx.x * 256 + threadIdx.x;  // 0 .. 393215
  int kc = id / NW3;                        // 0..127 : chunk of 8 k's
  int n = id - kc * NW3;                    // original column; lanes consecutive -> coalesced reads
  union { u16 u[8]; uint4 v; } p;
#pragma unroll
  for (int i = 0; i < 8; ++i) p.u[i] = f2bf(W[(kc * 8 + i) * NW3 + n]);
  int h = n & 15, hd = (n & 1023) >> 4;
  int np = (n & ~1023) + h * 64 + hd;       // permuted row
  *(uint4*)(Wt + np * DIM + kc * 8) = p.v;
}

// ---------------- QKV GEMM: [4096x1024]x[1024x3072]+b, bf16 MFMA ----------------
// 128x128 tile, BK=64, global_load_lds w/ XOR-swizzled 16B chunks.
// Columns are head-grouped (see conv_wt), so epilogue stores are dense:
// Q/K -> [b,h,s,hd] (32B segments per quad-row), V -> [b,h,hd,s] (uint2 along s).
__global__ __launch_bounds__(256) void gemm_qkv_kernel(
    const u16* __restrict__ Ab, const u16* __restrict__ Bt, const float* __restrict__ bias,
    u16* __restrict__ Q, u16* __restrict__ K, u16* __restrict__ Vt) {
  __shared__ __align__(16) u16 Al[128 * 64];
  __shared__ __align__(16) u16 Bl[128 * 64];
  const int t = threadIdx.x;
  const int lane = t & 63, wave = t >> 6;
  const int c = lane & 15, quad = lane >> 4;
  const int tm = blockIdx.x / 24, tn = blockIdx.x - tm * 24;
  const int wm = (wave >> 1) * 64, wn = (wave & 1) * 64;

  const char* Abase = (const char*)(Ab + (size_t)tm * 128 * DIM);
  const char* Bbase = (const char*)(Bt + (size_t)tn * 128 * DIM);

  f32x4 z = {0.f, 0.f, 0.f, 0.f};
  f32x4 acc[4][4];
#pragma unroll
  for (int i = 0; i < 4; ++i)
#pragma unroll
    for (int j = 0; j < 4; ++j) acc[i][j] = z;

  for (int kt = 0; kt < 16; ++kt) {
    __syncthreads();
    const int koff = kt * 128;  // byte offset of k0 within a row
#pragma unroll
    for (int r = 0; r < 4; ++r) {
      int l = r * 256 + t;          // 16B chunk id, wave-contiguous
      int row = l >> 3, pos = l & 7;
      int kc = pos ^ (row & 7);     // XOR swizzle (global side)
      GLL16(Abase + row * 2048 + koff + kc * 16, (char*)Al + l * 16);
      GLL16(Bbase + row * 2048 + koff + kc * 16, (char*)Bl + l * 16);
    }
    __syncthreads();
#pragma unroll
    for (int ks = 0; ks < 2; ++ks) {
      bf16x8 af[4], bfr[4];
#pragma unroll
      for (int mt = 0; mt < 4; ++mt) {
        int row = wm + mt * 16 + c;
        int kc = (ks * 4 + quad) ^ (row & 7);
        af[mt] = *(const bf16x8*)((const char*)Al + row * 128 + kc * 16);
      }
#pragma unroll
      for (int nt = 0; nt < 4; ++nt) {
        int row = wn + nt * 16 + c;
        int kc = (ks * 4 + quad) ^ (row & 7);
        bfr[nt] = *(const bf16x8*)((const char*)Bl + row * 128 + kc * 16);
      }
#pragma unroll
      for (int mt = 0; mt < 4; ++mt)
#pragma unroll
        for (int nt = 0; nt < 4; ++nt)
          acc[mt][nt] = MFMA_BF16(af[mt], bfr[nt], acc[mt][nt]);
    }
  }

  // Epilogue: C/D layout col = lane&15, row = quad*4 + reg (m89-verified).
  // Permuted column np: which = np>>10, h = (np&1023)>>6, hd = np&63.
#pragma unroll
  for (int nt = 0; nt < 4; ++nt) {
    int np = tn * 128 + wn + nt * 16 + c;
    int which = np >> 10;           // wave-uniform (128-col tile within one of Q/K/V)
    int rem = np & 1023;
    int h = rem >> 6, hd = rem & 63;
    float bv = bias[(np & ~1023) + hd * 16 + h];  // bias is in ORIGINAL column order
#pragma unroll
    for (int mt = 0; mt < 4; ++mt) {
      int mbase = tm * 128 + wm + mt * 16 + quad * 4;
      int bI = mbase >> 11;
      int s0 = mbase & 2047;
      if (which == 2) {
        union { u16 u[4]; uint2 v; } p;
#pragma unroll
        for (int r = 0; r < 4; ++r) p.u[r] = f2bf(acc[mt][nt][r] + bv);
        *(uint2*)(Vt + ((size_t)(bI * NH + h) * HD + hd) * SEQ + s0) = p.v;  // [b,h,hd,s]
      } else {
        u16* dst = (which == 0) ? Q : K;
#pragma unroll
        for (int r = 0; r < 4; ++r)
          dst[((size_t)(bI * NH + h) * SEQ + (s0 + r)) * HD + hd] = f2bf(acc[mt][nt][r] + bv);
      }
    }
  }
}

// ---------------- Flash attention (register-staged K/V prefetch) ----------------
// block = (b, h, 128 q rows), 4 waves x 32 q rows. Computes S^T = K*Q^T so that
// P^T's C-layout regs are consecutive s_k -> b64 LDS writes, b128 B-frag reads
// for O^T = V^T * P^T. K/V tiles for kt+1 are prefetched into REGISTERS during
// compute of kt (plain global_load_dwordx4 stays in flight across s_barrier,
// unlike global_load_lds which forces a vmcnt(0) drain at the barrier), then
// ds_write_b128'd at the top of the next iteration.
#define CSC 0.18033688011112042f  // 0.125 * log2(e)

__global__ __launch_bounds__(256) void attn_kernel(
    const u16* __restrict__ Q, const u16* __restrict__ K,
    const u16* __restrict__ Vt, float* __restrict__ Out) {
  __shared__ __align__(16) u16 Kl[128 * 64];       // 16 KB (also Q staging)
  __shared__ __align__(16) u16 Vl[64 * 128];       // 16 KB  V^T tile [hd][s_k]
  __shared__ __align__(16) char Pl[4 * 32 * 256];  // 32 KB, per-wave P^T [s_q][s_k]
  const int t = threadIdx.x;
  const int lane = t & 63, wave = t >> 6;
  const int c = lane & 15, quad = lane >> 4;
  const int qt = blockIdx.x & 15, bh = blockIdx.x >> 4;
  const int h = bh & 15, b = bh >> 4;

  const u16* Qb = Q + ((size_t)bh * SEQ + qt * 128) * HD;
  const char* Kb = (const char*)(K + (size_t)bh * SEQ * HD);
  const char* Vb = (const char*)(Vt + (size_t)bh * HD * SEQ);

  // stage Q tile through Kl via GLL (one-time), pull B-operand frags
#pragma unroll
  for (int r = 0; r < 4; ++r) {
    int l = r * 256 + t;
    int row = l >> 3, pos = l & 7;
    int kc = pos ^ (row & 7);
    GLL16((const char*)Qb + row * 128 + kc * 16, (char*)Kl + l * 16);
  }

  // register prefetch buffers + first K/V tile loads (kt=0)
  uint4 kv[4], vv[4];
#pragma unroll
  for (int r = 0; r < 4; ++r) {
    int l = r * 256 + t;
    { int row = l >> 3, pos = l & 7; int kc = pos ^ (row & 7);
      kv[r] = *(const uint4*)(Kb + row * 128 + kc * 16); }
    { int row = l >> 4, pos = l & 15; int kc = pos ^ (row & 15);
      vv[r] = *(const uint4*)(Vb + row * 4096 + kc * 16); }
  }

  __syncthreads();  // GLL drain: Q tile visible
  bf16x8 qf[2][2];
#pragma unroll
  for (int nt = 0; nt < 2; ++nt)
#pragma unroll
    for (int ks = 0; ks < 2; ++ks) {
      int row = wave * 32 + nt * 16 + c;
      int kc = (ks * 4 + quad) ^ (row & 7);
      qf[nt][ks] = *(const bf16x8*)((const char*)Kl + row * 128 + kc * 16);
    }

  float mM[2] = {-__builtin_inff(), -__builtin_inff()};
  float lS[2] = {0.f, 0.f};
  f32x4 z = {0.f, 0.f, 0.f, 0.f};
  f32x4 accO[4][2];
#pragma unroll
  for (int i = 0; i < 4; ++i) { accO[i][0] = z; accO[i][1] = z; }
  char* Pw = Pl + wave * 8192;
  const int e = 2 * (c & 7);  // even XOR key for 8B-granule swizzle (pair-preserving)

  for (int kt = 0; kt < 16; ++kt) {
    __syncthreads();  // all waves done reading Kl/Vl (kt=0: done reading qf)
    // commit prefetched kt tile to LDS (lane-contiguous b128, conflict-free)
#pragma unroll
    for (int r = 0; r < 4; ++r) {
      *(uint4*)((char*)Kl + (r * 256 + t) * 16) = kv[r];
      *(uint4*)((char*)Vl + (r * 256 + t) * 16) = vv[r];
    }
    // issue kt+1 loads; they stay in flight across the barrier + compute
    if (kt < 15) {
      const char* Ktb = Kb + (size_t)(kt + 1) * 16384;  // 128 rows * 128B
      const char* Vtb = Vb + (size_t)(kt + 1) * 256;    // 128 cols * 2B into 4096B rows
#pragma unroll
      for (int r = 0; r < 4; ++r) {
        int l = r * 256 + t;
        { int row = l >> 3, pos = l & 7; int kc = pos ^ (row & 7);
          kv[r] = *(const uint4*)(Ktb + row * 128 + kc * 16); }
        { int row = l >> 4, pos = l & 15; int kc = pos ^ (row & 15);
          vv[r] = *(const uint4*)(Vtb + row * 4096 + kc * 16); }
      }
    }
    __syncthreads();  // Kl/Vl writes visible

    // S^T = K * Q^T : m = s_k (128 -> 8 tiles), n = s_q (32 -> 2 tiles), k = hd (64)
    f32x4 sT[8][2];
#pragma unroll
    for (int mt = 0; mt < 8; ++mt) { sT[mt][0] = z; sT[mt][1] = z; }
#pragma unroll
    for (int mt = 0; mt < 8; ++mt) {
#pragma unroll
      for (int ks = 0; ks < 2; ++ks) {
        int row = mt * 16 + c;
        int kc = (ks * 4 + quad) ^ (row & 7);
        bf16x8 kf = *(const bf16x8*)((const char*)Kl + row * 128 + kc * 16);
        sT[mt][0] = MFMA_BF16(kf, qf[0][ks], sT[mt][0]);
        sT[mt][1] = MFMA_BF16(kf, qf[1][ks], sT[mt][1]);
      }
    }

    // online softmax over s_k; per-lane state for s_q = nt*16 + c
#pragma unroll
    for (int nt = 0; nt < 2; ++nt) {
      float mx = -__builtin_inff();
#pragma unroll
      for (int mt = 0; mt < 8; ++mt)
#pragma unroll
        for (int r = 0; r < 4; ++r) mx = fmaxf(mx, sT[mt][nt][r]);
      mx = fmaxf(mx, __shfl_xor(mx, 16));
      mx = fmaxf(mx, __shfl_xor(mx, 32));
      float mnew = fmaxf(mM[nt], mx);
      float alpha = fexp2((mM[nt] - mnew) * CSC);  // exp2(-inf)=0 on first tile
      mM[nt] = mnew;
      float mc = mnew * CSC;
      float rs = 0.f;
#pragma unroll
      for (int mt = 0; mt < 8; ++mt)
#pragma unroll
        for (int r = 0; r < 4; ++r) {
          float p = fexp2(sT[mt][nt][r] * CSC - mc);
          sT[mt][nt][r] = p;
          rs += p;
        }
      rs += __shfl_xor(rs, 16);
      rs += __shfl_xor(rs, 32);
      lS[nt] = lS[nt] * alpha + rs;
#pragma unroll
      for (int mt = 0; mt < 4; ++mt)
#pragma unroll
        for (int r = 0; r < 4; ++r) accO[mt][nt][r] *= alpha;
      // write P^T[s_k][s_q] : regs are consecutive s_k -> packed b64 write
#pragma unroll
      for (int mt = 0; mt < 8; ++mt) {
        union { u16 u[4]; uint2 v; } p;
#pragma unroll
        for (int r = 0; r < 4; ++r) p.u[r] = f2bf(sT[mt][nt][r]);
        int g = 4 * mt + quad;                       // 8B granule along s_k
        *(uint2*)(Pw + (nt * 16 + c) * 256 + (g ^ e) * 8) = p.v;
      }
    }

    // O^T += V^T * P^T : m = hd (64 -> 4 tiles), n = s_q (2 tiles), k = s_k (128 -> 4 steps)
#pragma unroll
    for (int ks = 0; ks < 4; ++ks) {
      bf16x8 pf[2];
#pragma unroll
      for (int nt = 0; nt < 2; ++nt) {
        int g2 = 8 * ks + 2 * quad;                  // even -> swizzled pair stays adjacent
        pf[nt] = *(const bf16x8*)(Pw + (nt * 16 + c) * 256 + (g2 ^ e) * 8);
      }
#pragma unroll
      for (int mt = 0; mt < 4; ++mt) {
        int row = mt * 16 + c;
        int kc = (ks * 4 + quad) ^ (row & 15);
        bf16x8 vf = *(const bf16x8*)((const char*)Vl + row * 256 + kc * 16);
        accO[mt][0] = MFMA_BF16(vf, pf[0], accO[mt][0]);
        accO[mt][1] = MFMA_BF16(vf, pf[1], accO[mt][1]);
      }
    }
  }

  // epilogue: O^T C-layout -> out[b][s][h*64+hd], 4 consecutive hd per reg quad -> float4
#pragma unroll
  for (int nt = 0; nt < 2; ++nt) {
    float inv = 1.f / lS[nt];
    int s = qt * 128 + wave * 32 + nt * 16 + c;
#pragma unroll
    for (int mt = 0; mt < 4; ++mt) {
      float4 o;
      o.x = accO[mt][nt][0] * inv;
      o.y = accO[mt][nt][1] * inv;
      o.z = accO[mt][nt][2] * inv;
      o.w = accO[mt][nt][3] * inv;
      size_t off = ((size_t)(b * SEQ + s)) * DIM + h * HD + mt * 16 + quad * 4;
      *(float4*)(Out + off) = o;
    }
  }
}

extern "C" void kernel_launch(void* const* d_in, const int* in_sizes, int n_in,
                              void* d_out, int out_size, void* d_ws, size_t ws_size,
                              hipStream_t stream) {
  (void)in_sizes; (void)n_in; (void)out_size; (void)ws_size;
  const float* emb = (const float*)d_in[0];
  const float* W = (const float*)d_in[1];
  const float* bias = (const float*)d_in[2];
  float* out = (float*)d_out;
  char* ws = (char*)d_ws;
  // ws layout (bytes): Abf 8 MB | Wt 6 MB | Q 8 MB | K 8 MB | Vt 8 MB  (total ~38 MB)
  u16* Ab = (u16*)ws;
  u16* Wt = (u16*)(ws + 8388608);
  u16* Qd = (u16*)(ws + 14680064);
  u16* Kd = (u16*)(ws + 23068672);
  u16* Vd = (u16*)(ws + 31457280);

  conv_a_kernel<<<4096, 256, 0, stream>>>(emb, Ab);        // 4096*1024 elems / 4 per thread
  conv_wt_kernel<<<1536, 256, 0, stream>>>(W, Wt);         // 3072*128 chunk-threads
  gemm_qkv_kernel<<<768, 256, 0, stream>>>(Ab, Wt, bias, Qd, Kd, Vd);  // 32x24 tiles
  attn_kernel<<<512, 256, 0, stream>>>(Qd, Kd, Vd, out);   // 2*16*16 (b,h,qtile)
}